// Round 5
// baseline (131.685 us; speedup 1.0000x reference)
//
#include <hip/hip_runtime.h>
#include <hip/hip_bf16.h>

constexpr int CH = 128;    // channels
constexpr int NPOS = 4096; // h*w
constexpr int NB = 4;      // batch
constexpr int SPLITS = 8;  // split-K factor for flash attention

typedef __bf16 bf16x8 __attribute__((ext_vector_type(8)));
typedef float f32x4v __attribute__((ext_vector_type(4)));
typedef float f32x16 __attribute__((ext_vector_type(16)));

// (1/sqrt(128)) * log2(e): fold softmax scale into Qb so MFMA emits exp2-domain
constexpr float CSC = 0.08838834764831845f * 1.4426950408889634f;

// Frag-native layout for Q/K: [b][tile16 = pos>>4][kf = c>>5][lane][j]
// lane = (pos&15) + 16*((c>>3)&3), j = c&7. One (tile,kf) chunk = contiguous
// 1KB = one lane-indexed bf16x8 load for mfma_16x16x32 A/B operands.

// ---------------------------------------------------------------------------
// Fuse kernel: Wqk = Wk @ Wq, bqk = Wk@bq + bk; bf16 copies of Wq, Wqk.
// ---------------------------------------------------------------------------
__global__ __launch_bounds__(128) void fuse_w_kernel(
    const float* __restrict__ Wq, const float* __restrict__ bq,
    const float* __restrict__ Wk, const float* __restrict__ bk,
    __bf16* __restrict__ Wqb, __bf16* __restrict__ Wqkb,
    float* __restrict__ bqk) {
  __shared__ float red[CH];
  const int o = blockIdx.x;
  const int i = threadIdx.x;
  float acc = 0.f;
#pragma unroll 8
  for (int m = 0; m < CH; m++) acc += Wk[o * CH + m] * Wq[m * CH + i];
  Wqkb[o * CH + i] = (__bf16)acc;
  Wqb[o * CH + i] = (__bf16)Wq[o * CH + i];
  red[i] = Wk[o * CH + i] * bq[i];
  __syncthreads();
  if (i == 0) {
    float s = 0.f;
    for (int m = 0; m < CH; m++) s += red[m];
    bqk[o] = s + bk[o];
  }
}

// ---------------------------------------------------------------------------
// Projection via mfma_32x32x16_bf16, one wave per 32-pos tile, frag-native
// output. 1-D grid with XCD-affinity: batch b -> XCDs {2b,2b+1} so Q/K dirty
// lines land in the L2 that attn's batch-b blocks will read.
// ---------------------------------------------------------------------------
__global__ __launch_bounds__(64) void proj_kernel(
    const float* __restrict__ feature0, const __bf16* __restrict__ Wqb,
    const float* __restrict__ bq, const __bf16* __restrict__ Wqkb,
    const float* __restrict__ bqk, __bf16* __restrict__ Qf,
    __bf16* __restrict__ Kf) {
  const int bid = blockIdx.x;  // 512 blocks
  const int b = (bid >> 1) & 3;
  const int u = (bid >> 3) * 2 + (bid & 1);  // 0..127 per batch
  const int lane = threadIdx.x;
  const int half = lane >> 5, l31 = lane & 31;
  const int pos0 = u * 32;
  const int pos = pos0 + l31;

  bf16x8 A[8];
#pragma unroll
  for (int ks = 0; ks < 8; ks++) {
    float v[8];
#pragma unroll
    for (int j = 0; j < 8; j++)
      v[j] = feature0[(size_t)(b * CH + ks * 16 + half * 8 + j) * NPOS + pos];
#pragma unroll
    for (int j = 0; j < 8; j++) A[ks][j] = (__bf16)v[j];
  }

#pragma unroll
  for (int z = 0; z < 2; z++) {
    const __bf16* W = z ? Wqkb : Wqb;
    const float* bias = z ? bqk : bq;
    __bf16* Out = z ? Kf : Qf;
    const float scale = z ? 1.0f : CSC;
#pragma unroll
    for (int n = 0; n < 4; n++) {
      const int co = n * 32 + l31;
      const bf16x8* Bp = (const bf16x8*)(W + co * CH + half * 8);
      f32x16 c = {0.f, 0.f, 0.f, 0.f, 0.f, 0.f, 0.f, 0.f,
                  0.f, 0.f, 0.f, 0.f, 0.f, 0.f, 0.f, 0.f};
#pragma unroll
      for (int ks = 0; ks < 8; ks++)
        c = __builtin_amdgcn_mfma_f32_32x32x16_bf16(A[ks], Bp[ks * 2], c, 0, 0,
                                                    0);
      const float bv = bias[co];
      const int quadc = l31 >> 3;
      const int j = l31 & 7;
#pragma unroll
      for (int r = 0; r < 16; r++) {
        int roff = (r & 3) + 8 * (r >> 2) + 4 * half;
        int nt = (pos0 >> 4) + (roff >> 4);
        int lp = (roff & 15) + 16 * quadc;
        Out[((((size_t)(b * (NPOS / 16) + nt)) * 4 + n) * 64 + lp) * 8 + j] =
            (__bf16)((c[r] + bv) * scale);
      }
    }
  }
}

// ---------------------------------------------------------------------------
// Flash attention, split-K, no running max (scores exp2-domain bounded;
// verified R1-R4). mfma_16x16x32_bf16; frag-native 1KB coalesced B loads.
// XCD-affinity grid (batch b -> XCDs {2b,2b+1}) keeps K+Q L2-resident.
// Explicit 2-deep register pipeline: next iteration's 8 B-frags (32 VGPRs)
// load while current iteration computes; launch_bounds(256,4) = 128 VGPR cap.
// ---------------------------------------------------------------------------
__global__ __launch_bounds__(256, 4) void attn_kernel(
    const __bf16* __restrict__ Qf, const __bf16* __restrict__ Kf,
    const float* __restrict__ flow, float* __restrict__ part) {
  __shared__ float red[64 * 3];

  const int bid = blockIdx.x;  // 2048 blocks
  const int b = (bid >> 1) & 3;
  const int u = (bid >> 3) * 2 + (bid & 1);  // 0..511 per batch
  const int split = u >> 6;
  const int qg = u & 63;

  const int tid = threadIdx.x;
  const int wave = tid >> 6, lane = tid & 63;
  const int quad = lane >> 4, l15 = lane & 15;
  const int qt = qg * 4 + wave;               // global 16-row q-tile index
  const int kbase = split * (NPOS / SPLITS);  // 512 keys per split
  constexpr int NIT = NPOS / SPLITS / 32;     // 16 iters x 32 keys

  const bf16x8* Qp =
      (const bf16x8*)Qf + ((size_t)(b * (NPOS / 16) + qt) * 4) * 64 + lane;
  bf16x8 qf[4];
#pragma unroll
  for (int kf = 0; kf < 4; kf++) qf[kf] = Qp[kf * 64];

  const bf16x8* Kp =
      (const bf16x8*)Kf + ((size_t)(b * (NPOS / 16) + (kbase >> 4)) * 4) * 64 +
      lane;
  const float* fl0 = flow + (size_t)(b * 2 + 0) * NPOS + kbase;
  const float* fl1 = flow + (size_t)(b * 2 + 1) * NPOS + kbase;

  float ls[4], a0[4], a1[4];
#pragma unroll
  for (int r = 0; r < 4; r++) {
    ls[r] = 0.f;
    a0[r] = 0.f;
    a1[r] = 0.f;
  }

  bf16x8 B0[8], B1[8];
  float f0[4], f1[4];

  auto load = [&](bf16x8(&B)[8], float(&fv)[4], int it) {
#pragma unroll
    for (int kf = 0; kf < 4; kf++) {
      B[kf] = Kp[((it * 2 + 0) * 4 + kf) * 64];
      B[4 + kf] = Kp[((it * 2 + 1) * 4 + kf) * 64];
    }
    fv[0] = fl0[it * 32 + l15];
    fv[1] = fl1[it * 32 + l15];
    fv[2] = fl0[it * 32 + 16 + l15];
    fv[3] = fl1[it * 32 + 16 + l15];
  };
  auto compute = [&](const bf16x8(&B)[8], const float(&fv)[4]) {
    f32x4v ca = {0.f, 0.f, 0.f, 0.f}, cb = {0.f, 0.f, 0.f, 0.f};
#pragma unroll
    for (int kf = 0; kf < 4; kf++)
      ca = __builtin_amdgcn_mfma_f32_16x16x32_bf16(qf[kf], B[kf], ca, 0, 0, 0);
#pragma unroll
    for (int kf = 0; kf < 4; kf++)
      cb = __builtin_amdgcn_mfma_f32_16x16x32_bf16(qf[kf], B[4 + kf], cb, 0, 0,
                                                   0);
#pragma unroll
    for (int r = 0; r < 4; r++) {
      float pa = exp2f(ca[r]), pb = exp2f(cb[r]);
      ls[r] += pa + pb;
      a0[r] = fmaf(pa, fv[0], fmaf(pb, fv[2], a0[r]));
      a1[r] = fmaf(pa, fv[1], fmaf(pb, fv[3], a1[r]));
    }
  };

  load(B0, f0, 0);
#pragma unroll
  for (int it = 0; it < NIT; it += 2) {
    if (it + 1 < NIT) load(B1, f1, it + 1);
    compute(B0, f0);
    if (it + 2 < NIT) load(B0, f0, it + 2);
    if (it + 1 < NIT) compute(B1, f1);
  }

  // reduce across the 16 key-lanes (cols) within each quad-group
#pragma unroll
  for (int r = 0; r < 4; r++) {
#pragma unroll
    for (int st = 1; st < 16; st <<= 1) {
      ls[r] += __shfl_xor(ls[r], st, 64);
      a0[r] += __shfl_xor(a0[r], st, 64);
      a1[r] += __shfl_xor(a1[r], st, 64);
    }
  }
  if (l15 == 0) {
#pragma unroll
    for (int r = 0; r < 4; r++) {
      int ql = wave * 16 + quad * 4 + r;
      red[ql * 3 + 0] = ls[r];
      red[ql * 3 + 1] = a0[r];
      red[ql * 3 + 2] = a1[r];
    }
  }
  __syncthreads();
  for (int idx = tid; idx < 64 * 3; idx += 256) {
    int plane = idx >> 6, ql = idx & 63;
    part[((size_t)(plane * SPLITS + split) * NB + b) * NPOS + qg * 64 + ql] =
        red[ql * 3 + plane];
  }
}

// ---------------------------------------------------------------------------
// Combine: sum split partials per plane, normalize, write out[b][2][n].
// ---------------------------------------------------------------------------
__global__ __launch_bounds__(256) void combine_kernel(
    const float* __restrict__ part, float* __restrict__ out) {
  int t = blockIdx.x * 256 + threadIdx.x;  // 0 .. NB*NPOS-1
  int b = t >> 12, q = t & (NPOS - 1);
  float l = 0.f, x = 0.f, y = 0.f;
#pragma unroll
  for (int s = 0; s < SPLITS; s++) {
    l += part[((size_t)(0 * SPLITS + s) * NB + b) * NPOS + q];
    x += part[((size_t)(1 * SPLITS + s) * NB + b) * NPOS + q];
    y += part[((size_t)(2 * SPLITS + s) * NB + b) * NPOS + q];
  }
  float inv = 1.0f / l;
  out[(size_t)(b * 2 + 0) * NPOS + q] = x * inv;
  out[(size_t)(b * 2 + 1) * NPOS + q] = y * inv;
}

extern "C" void kernel_launch(void* const* d_in, const int* in_sizes, int n_in,
                              void* d_out, int out_size, void* d_ws,
                              size_t ws_size, hipStream_t stream) {
  const float* feature0 = (const float*)d_in[0];
  const float* flow = (const float*)d_in[1];
  const float* Wq = (const float*)d_in[2];
  const float* bq = (const float*)d_in[3];
  const float* Wk = (const float*)d_in[4];
  const float* bk = (const float*)d_in[5];
  float* out = (float*)d_out;

  char* ws = (char*)d_ws;
  __bf16* Qf = (__bf16*)ws;                                 // 4 MB
  __bf16* Kf = (__bf16*)(ws + (4 << 20));                   // 4 MB
  __bf16* Wqb = (__bf16*)(ws + (8 << 20));                  // 32 KB
  __bf16* Wqkb = (__bf16*)(ws + (8 << 20) + (32 << 10));    // 32 KB
  float* bqk = (float*)(ws + (8 << 20) + (64 << 10));       // 512 B
  float* part = (float*)(ws + (8 << 20) + (128 << 10));     // 1.5 MB

  fuse_w_kernel<<<dim3(CH), 128, 0, stream>>>(Wq, bq, Wk, bk, Wqb, Wqkb, bqk);
  proj_kernel<<<dim3(512), 64, 0, stream>>>(feature0, Wqb, bq, Wqkb, bqk, Qf,
                                            Kf);
  attn_kernel<<<dim3(2048), 256, 0, stream>>>(Qf, Kf, flow, part);
  combine_kernel<<<dim3(NB * NPOS / 256), 256, 0, stream>>>(part, out);
}

// Round 6
// 117.953 us; speedup vs baseline: 1.1164x; 1.1164x over previous
//
#include <hip/hip_runtime.h>
#include <hip/hip_bf16.h>

constexpr int CH = 128;    // channels
constexpr int NPOS = 4096; // h*w
constexpr int NB = 4;      // batch
constexpr int SPLITS = 8;  // split-K factor for flash attention

typedef __bf16 bf16x8 __attribute__((ext_vector_type(8)));
typedef float f32x16 __attribute__((ext_vector_type(16)));

// (1/sqrt(128)) * log2(e): fold softmax scale into Qb so MFMA emits exp2-domain
constexpr float CSC = 0.08838834764831845f * 1.4426950408889634f;

// Frag-native layout for Q/K (mfma_32x32x16 A/B operand order):
// [b][t32 = pos>>5][kf = c>>4][lane][j]; lane = (pos&31) + 32*((c>>3)&1),
// j = c&7. One (t32,kf) chunk = contiguous 1 KB = one lane-indexed bf16x8.

// Async global->LDS DMA, 16B per lane, LDS dst = wave-uniform base + lane*16.
__device__ __forceinline__ void async_copy16(const void* g, void* l) {
  auto gp = (const __attribute__((address_space(1))) unsigned int*)((uintptr_t)g);
  auto lp = (__attribute__((address_space(3))) unsigned int*)((uintptr_t)l);
  __builtin_amdgcn_global_load_lds(gp, lp, 16, 0, 0);
}

// ---------------------------------------------------------------------------
// Fuse kernel: Wqk = Wk @ Wq, bqk = Wk@bq + bk; bf16 copies of Wq, Wqk.
// ---------------------------------------------------------------------------
__global__ __launch_bounds__(128) void fuse_w_kernel(
    const float* __restrict__ Wq, const float* __restrict__ bq,
    const float* __restrict__ Wk, const float* __restrict__ bk,
    __bf16* __restrict__ Wqb, __bf16* __restrict__ Wqkb,
    float* __restrict__ bqk) {
  __shared__ float red[CH];
  const int o = blockIdx.x;
  const int i = threadIdx.x;
  float acc = 0.f;
#pragma unroll 8
  for (int m = 0; m < CH; m++) acc += Wk[o * CH + m] * Wq[m * CH + i];
  Wqkb[o * CH + i] = (__bf16)acc;
  Wqb[o * CH + i] = (__bf16)Wq[o * CH + i];
  red[i] = Wk[o * CH + i] * bq[i];
  __syncthreads();
  if (i == 0) {
    float s = 0.f;
    for (int m = 0; m < CH; m++) s += red[m];
    bqk[o] = s + bk[o];
  }
}

// ---------------------------------------------------------------------------
// Projection via mfma_32x32x16_bf16, one wave per 32-pos tile, frag-native
// output layout (above). XCD-affinity: batch b -> XCDs {2b,2b+1}.
// D[m=pos][n=co]: col=l31=co, roff=(r&3)+8*(r>>2)+4*half = pos offset in 32.
// ---------------------------------------------------------------------------
__global__ __launch_bounds__(64) void proj_kernel(
    const float* __restrict__ feature0, const __bf16* __restrict__ Wqb,
    const float* __restrict__ bq, const __bf16* __restrict__ Wqkb,
    const float* __restrict__ bqk, __bf16* __restrict__ Qf,
    __bf16* __restrict__ Kf) {
  const int bid = blockIdx.x;  // 512 blocks
  const int b = (bid >> 1) & 3;
  const int u = (bid >> 3) * 2 + (bid & 1);  // 0..127 per batch (= t32)
  const int lane = threadIdx.x;
  const int half = lane >> 5, l31 = lane & 31;
  const int pos = u * 32 + l31;

  bf16x8 A[8];
#pragma unroll
  for (int ks = 0; ks < 8; ks++) {
    float v[8];
#pragma unroll
    for (int j = 0; j < 8; j++)
      v[j] = feature0[(size_t)(b * CH + ks * 16 + half * 8 + j) * NPOS + pos];
#pragma unroll
    for (int j = 0; j < 8; j++) A[ks][j] = (__bf16)v[j];
  }

#pragma unroll
  for (int z = 0; z < 2; z++) {
    const __bf16* W = z ? Wqkb : Wqb;
    const float* bias = z ? bqk : bq;
    __bf16* Out = z ? Kf : Qf;
    const float scale = z ? 1.0f : CSC;
#pragma unroll
    for (int n = 0; n < 4; n++) {
      const int co = n * 32 + l31;
      const bf16x8* Bp = (const bf16x8*)(W + co * CH + half * 8);
      f32x16 c = {0.f, 0.f, 0.f, 0.f, 0.f, 0.f, 0.f, 0.f,
                  0.f, 0.f, 0.f, 0.f, 0.f, 0.f, 0.f, 0.f};
#pragma unroll
      for (int ks = 0; ks < 8; ks++)
        c = __builtin_amdgcn_mfma_f32_32x32x16_bf16(A[ks], Bp[ks * 2], c, 0, 0,
                                                    0);
      const float bv = bias[co];
      const int kf = n * 2 + (l31 >> 4);
      const int lanebit = (l31 >> 3) & 1;
      const int j = l31 & 7;
#pragma unroll
      for (int r = 0; r < 16; r++) {
        int roff = (r & 3) + 8 * (r >> 2) + 4 * half;  // pos offset in tile
        Out[((((size_t)(b * (NPOS / 32) + u)) * 8 + kf) * 64 +
             (roff + 32 * lanebit)) * 8 + j] = (__bf16)((c[r] + bv) * scale);
      }
    }
  }
}

// ---------------------------------------------------------------------------
// Flash attention, split-K, no running max (scores exp2-domain bounded;
// verified R1-R5). mfma_32x32x16_bf16: wave = 32 q rows, block = 128 q rows.
// K tiles (32 keys x 128 c = 8 KB) SHARED across the 4 waves via LDS,
// staged by global_load_lds DMA into a 4-deep circular buffer; one
// __syncthreads per tile (its vmcnt drain only waits DMA issued >=1 full
// iteration ago). Flow pre-staged to LDS once; key = lane&31 -> V scalar.
// C/D: col=lane&31=key, row=(r&3)+8*(r>>2)+4*(lane>>5) = q offset in 32.
// ---------------------------------------------------------------------------
__global__ __launch_bounds__(256, 4) void attn_kernel(
    const __bf16* __restrict__ Qf, const __bf16* __restrict__ Kf,
    const float* __restrict__ flow, float* __restrict__ part) {
  __shared__ __bf16 Klds[4][8 * 512];  // 4 x 8 KB circular buffer
  __shared__ float flds[2 * 512];      // split's flow values
  __shared__ float red[128 * 3];

  const int bid = blockIdx.x;  // 1024 blocks
  const int b = (bid >> 1) & 3;
  const int u = (bid >> 3) * 2 + (bid & 1);  // 0..255 per batch
  const int split = u >> 5;                  // 8 splits
  const int qg = u & 31;                     // 32 q-groups of 128 rows

  const int tid = threadIdx.x;
  const int wave = tid >> 6, lane = tid & 63;
  const int half = lane >> 5, l31 = lane & 31;
  const int kbase = split * (NPOS / SPLITS);  // 512 keys per split
  constexpr int NT = NPOS / SPLITS / 32;      // 16 tiles of 32 keys

  // stage flow for this split into LDS (one-time)
  {
    const float* fl0 = flow + (size_t)(b * 2 + 0) * NPOS + kbase;
    const float* fl1 = flow + (size_t)(b * 2 + 1) * NPOS + kbase;
    for (int i = tid; i < 512; i += 256) {
      flds[i] = fl0[i];
      flds[512 + i] = fl1[i];
    }
  }

  // Q fragments: wave's 32 q rows = tile qt
  const int qt = qg * 4 + wave;  // 0..127
  bf16x8 qf[8];
  {
    const bf16x8* Qp =
        (const bf16x8*)Qf + ((size_t)(b * (NPOS / 32) + qt) * 8) * 64 + lane;
#pragma unroll
    for (int kf = 0; kf < 8; kf++) qf[kf] = Qp[kf * 64];
  }

  __syncthreads();  // flds visible

  // K tile base for this (b, split): tiles are 8*512 bf16 = 8 KB each
  const __bf16* Ktb =
      Kf + ((size_t)(b * (NPOS / 32) + (kbase >> 5)) * 8) * 512;

  // prolog: DMA tiles 0,1,2; wave w stages chunks 2w, 2w+1
  auto issue = [&](int t) {
    const __bf16* g = Ktb + (size_t)t * (8 * 512);
#pragma unroll
    for (int cc = 0; cc < 2; cc++) {
      int chunk = wave * 2 + cc;
      async_copy16(g + chunk * 512 + lane * 8,
                   &Klds[t & 3][chunk * 512 + lane * 8]);
    }
  };
  issue(0);
  issue(1);
  issue(2);

  float ls[16], a0[16], a1[16];
#pragma unroll
  for (int r = 0; r < 16; r++) {
    ls[r] = 0.f;
    a0[r] = 0.f;
    a1[r] = 0.f;
  }

  for (int t = 0; t < NT; t++) {
    __syncthreads();  // tile t ready (vmcnt drained); buf[(t+3)&3] free
    if (t + 3 < NT) issue(t + 3);

    const __bf16* kb = &Klds[t & 3][0];
    f32x16 c = {0.f, 0.f, 0.f, 0.f, 0.f, 0.f, 0.f, 0.f,
                0.f, 0.f, 0.f, 0.f, 0.f, 0.f, 0.f, 0.f};
#pragma unroll
    for (int kf = 0; kf < 8; kf++) {
      bf16x8 bfrag = *(const bf16x8*)(kb + kf * 512 + lane * 8);
      c = __builtin_amdgcn_mfma_f32_32x32x16_bf16(qf[kf], bfrag, c, 0, 0, 0);
    }
    const float v0 = flds[t * 32 + l31];
    const float v1 = flds[512 + t * 32 + l31];
#pragma unroll
    for (int r = 0; r < 16; r++) {
      float p = exp2f(c[r]);
      ls[r] += p;
      a0[r] = fmaf(p, v0, a0[r]);
      a1[r] = fmaf(p, v1, a1[r]);
    }
  }

  // reduce across the 32 key-lanes (butterfly stays within each 32-lane half)
#pragma unroll
  for (int r = 0; r < 16; r++) {
#pragma unroll
    for (int st = 1; st < 32; st <<= 1) {
      ls[r] += __shfl_xor(ls[r], st, 64);
      a0[r] += __shfl_xor(a0[r], st, 64);
      a1[r] += __shfl_xor(a1[r], st, 64);
    }
  }
  if (l31 == 0) {
#pragma unroll
    for (int r = 0; r < 16; r++) {
      int ql = wave * 32 + (r & 3) + 8 * (r >> 2) + 4 * half;
      red[ql * 3 + 0] = ls[r];
      red[ql * 3 + 1] = a0[r];
      red[ql * 3 + 2] = a1[r];
    }
  }
  __syncthreads();
  for (int idx = tid; idx < 128 * 3; idx += 256) {
    int plane = idx / 128, ql = idx % 128;
    part[((size_t)(plane * SPLITS + split) * NB + b) * NPOS + qg * 128 + ql] =
        red[ql * 3 + plane];
  }
}

// ---------------------------------------------------------------------------
// Combine: sum split partials per plane, normalize, write out[b][2][n].
// ---------------------------------------------------------------------------
__global__ __launch_bounds__(256) void combine_kernel(
    const float* __restrict__ part, float* __restrict__ out) {
  int t = blockIdx.x * 256 + threadIdx.x;  // 0 .. NB*NPOS-1
  int b = t >> 12, q = t & (NPOS - 1);
  float l = 0.f, x = 0.f, y = 0.f;
#pragma unroll
  for (int s = 0; s < SPLITS; s++) {
    l += part[((size_t)(0 * SPLITS + s) * NB + b) * NPOS + q];
    x += part[((size_t)(1 * SPLITS + s) * NB + b) * NPOS + q];
    y += part[((size_t)(2 * SPLITS + s) * NB + b) * NPOS + q];
  }
  float inv = 1.0f / l;
  out[(size_t)(b * 2 + 0) * NPOS + q] = x * inv;
  out[(size_t)(b * 2 + 1) * NPOS + q] = y * inv;
}

extern "C" void kernel_launch(void* const* d_in, const int* in_sizes, int n_in,
                              void* d_out, int out_size, void* d_ws,
                              size_t ws_size, hipStream_t stream) {
  const float* feature0 = (const float*)d_in[0];
  const float* flow = (const float*)d_in[1];
  const float* Wq = (const float*)d_in[2];
  const float* bq = (const float*)d_in[3];
  const float* Wk = (const float*)d_in[4];
  const float* bk = (const float*)d_in[5];
  float* out = (float*)d_out;

  char* ws = (char*)d_ws;
  __bf16* Qf = (__bf16*)ws;                                 // 4 MB
  __bf16* Kf = (__bf16*)(ws + (4 << 20));                   // 4 MB
  __bf16* Wqb = (__bf16*)(ws + (8 << 20));                  // 32 KB
  __bf16* Wqkb = (__bf16*)(ws + (8 << 20) + (32 << 10));    // 32 KB
  float* bqk = (float*)(ws + (8 << 20) + (64 << 10));       // 512 B
  float* part = (float*)(ws + (8 << 20) + (128 << 10));     // 1.5 MB

  fuse_w_kernel<<<dim3(CH), 128, 0, stream>>>(Wq, bq, Wk, bk, Wqb, Wqkb, bqk);
  proj_kernel<<<dim3(512), 64, 0, stream>>>(feature0, Wqb, bq, Wqkb, bqk, Qf,
                                            Kf);
  attn_kernel<<<dim3(1024), 256, 0, stream>>>(Qf, Kf, flow, part);
  combine_kernel<<<dim3(NB * NPOS / 256), 256, 0, stream>>>(part, out);
}

// Round 7
// 114.313 us; speedup vs baseline: 1.1520x; 1.0318x over previous
//
#include <hip/hip_runtime.h>
#include <hip/hip_bf16.h>

constexpr int CH = 128;    // channels
constexpr int NPOS = 4096; // h*w
constexpr int NB = 4;      // batch
constexpr int SPLITS = 8;  // split-K factor for flash attention

typedef __bf16 bf16x8 __attribute__((ext_vector_type(8)));
typedef float f32x2 __attribute__((ext_vector_type(2)));
typedef float f32x16 __attribute__((ext_vector_type(16)));

// (1/sqrt(128)) * log2(e): fold softmax scale into Qb so MFMA emits exp2-domain
constexpr float CSC = 0.08838834764831845f * 1.4426950408889634f;

// Frag-native layout for Q/K (mfma_32x32x16 A/B operand order):
// [b][t32 = pos>>5][kf = c>>4][lane][j]; lane = (pos&31) + 32*((c>>3)&1),
// j = c&7. One (t32,kf) chunk = contiguous 1 KB = one lane-indexed bf16x8.

// Async global->LDS DMA, 16B per lane, LDS dst = wave-uniform base + lane*16.
__device__ __forceinline__ void async_copy16(const void* g, void* l) {
  auto gp = (const __attribute__((address_space(1))) unsigned int*)((uintptr_t)g);
  auto lp = (__attribute__((address_space(3))) unsigned int*)((uintptr_t)l);
  __builtin_amdgcn_global_load_lds(gp, lp, 16, 0, 0);
}

// Barrier that does NOT drain the DMA queue: waits only until <=N vmem ops
// outstanding (tile-t's DMAs are the oldest), keeps prefetches in flight.
#define PIPE_BARRIER(N)                                              \
  asm volatile("s_waitcnt vmcnt(" #N ") lgkmcnt(0)\n\ts_barrier" ::: "memory")

// ---------------------------------------------------------------------------
// Fuse kernel: Wqk = Wk @ Wq, bqk = Wk@bq + bk; bf16 copies of Wq, Wqk.
// ---------------------------------------------------------------------------
__global__ __launch_bounds__(128) void fuse_w_kernel(
    const float* __restrict__ Wq, const float* __restrict__ bq,
    const float* __restrict__ Wk, const float* __restrict__ bk,
    __bf16* __restrict__ Wqb, __bf16* __restrict__ Wqkb,
    float* __restrict__ bqk) {
  __shared__ float red[CH];
  const int o = blockIdx.x;
  const int i = threadIdx.x;
  float acc = 0.f;
#pragma unroll 8
  for (int m = 0; m < CH; m++) acc += Wk[o * CH + m] * Wq[m * CH + i];
  Wqkb[o * CH + i] = (__bf16)acc;
  Wqb[o * CH + i] = (__bf16)Wq[o * CH + i];
  red[i] = Wk[o * CH + i] * bq[i];
  __syncthreads();
  if (i == 0) {
    float s = 0.f;
    for (int m = 0; m < CH; m++) s += red[m];
    bqk[o] = s + bk[o];
  }
}

// ---------------------------------------------------------------------------
// Projection via mfma_32x32x16_bf16, one wave per 32-pos tile, frag-native
// output layout (above). XCD-affinity: batch b -> XCDs {2b,2b+1}.
// ---------------------------------------------------------------------------
__global__ __launch_bounds__(64) void proj_kernel(
    const float* __restrict__ feature0, const __bf16* __restrict__ Wqb,
    const float* __restrict__ bq, const __bf16* __restrict__ Wqkb,
    const float* __restrict__ bqk, __bf16* __restrict__ Qf,
    __bf16* __restrict__ Kf) {
  const int bid = blockIdx.x;  // 512 blocks
  const int b = (bid >> 1) & 3;
  const int u = (bid >> 3) * 2 + (bid & 1);  // 0..127 per batch (= t32)
  const int lane = threadIdx.x;
  const int half = lane >> 5, l31 = lane & 31;
  const int pos = u * 32 + l31;

  bf16x8 A[8];
#pragma unroll
  for (int ks = 0; ks < 8; ks++) {
    float v[8];
#pragma unroll
    for (int j = 0; j < 8; j++)
      v[j] = feature0[(size_t)(b * CH + ks * 16 + half * 8 + j) * NPOS + pos];
#pragma unroll
    for (int j = 0; j < 8; j++) A[ks][j] = (__bf16)v[j];
  }

#pragma unroll
  for (int z = 0; z < 2; z++) {
    const __bf16* W = z ? Wqkb : Wqb;
    const float* bias = z ? bqk : bq;
    __bf16* Out = z ? Kf : Qf;
    const float scale = z ? 1.0f : CSC;
#pragma unroll
    for (int n = 0; n < 4; n++) {
      const int co = n * 32 + l31;
      const bf16x8* Bp = (const bf16x8*)(W + co * CH + half * 8);
      f32x16 c = {0.f, 0.f, 0.f, 0.f, 0.f, 0.f, 0.f, 0.f,
                  0.f, 0.f, 0.f, 0.f, 0.f, 0.f, 0.f, 0.f};
#pragma unroll
      for (int ks = 0; ks < 8; ks++)
        c = __builtin_amdgcn_mfma_f32_32x32x16_bf16(A[ks], Bp[ks * 2], c, 0, 0,
                                                    0);
      const float bv = bias[co];
      const int kf = n * 2 + (l31 >> 4);
      const int lanebit = (l31 >> 3) & 1;
      const int j = l31 & 7;
#pragma unroll
      for (int r = 0; r < 16; r++) {
        int roff = (r & 3) + 8 * (r >> 2) + 4 * half;  // pos offset in tile
        Out[((((size_t)(b * (NPOS / 32) + u)) * 8 + kf) * 64 +
             (roff + 32 * lanebit)) * 8 + j] = (__bf16)((c[r] + bv) * scale);
      }
    }
  }
}

// ---------------------------------------------------------------------------
// Flash attention, split-K, no running max (scores exp2-domain bounded;
// verified R1-R6). mfma_32x32x16_bf16: wave = 32 q rows, block = 128 q rows.
// K tiles (8 KB) shared across 4 waves via LDS, DMA'd into a 3-deep circular
// buffer. Raw s_waitcnt vmcnt(2)+s_barrier per tile keeps the t+1 prefetch
// IN FLIGHT across the barrier (no vmcnt(0) drain -> true pipeline).
// exp2 via __builtin_amdgcn_exp2f (bare v_exp_f32); a0/a1 as packed f32x2.
// ---------------------------------------------------------------------------
__global__ __launch_bounds__(256, 4) void attn_kernel(
    const __bf16* __restrict__ Qf, const __bf16* __restrict__ Kf,
    const float* __restrict__ flow, float* __restrict__ part) {
  __shared__ __bf16 Klds[3][8 * 512];  // 3 x 8 KB circular buffer
  __shared__ float flds[2 * 512];      // split's flow values
  __shared__ float red[128 * 3];

  const int bid = blockIdx.x;  // 1024 blocks
  const int b = (bid >> 1) & 3;
  const int u = (bid >> 3) * 2 + (bid & 1);  // 0..255 per batch
  const int split = u >> 5;                  // 8 splits
  const int qg = u & 31;                     // 32 q-groups of 128 rows

  const int tid = threadIdx.x;
  const int wave = tid >> 6, lane = tid & 63;
  const int half = lane >> 5, l31 = lane & 31;
  const int kbase = split * (NPOS / SPLITS);  // 512 keys per split
  constexpr int NT = NPOS / SPLITS / 32;      // 16 tiles of 32 keys

  // stage flow for this split into LDS (one-time; fenced by first barrier)
  {
    const float* fl0 = flow + (size_t)(b * 2 + 0) * NPOS + kbase;
    const float* fl1 = flow + (size_t)(b * 2 + 1) * NPOS + kbase;
    for (int i = tid; i < 512; i += 256) {
      flds[i] = fl0[i];
      flds[512 + i] = fl1[i];
    }
  }

  // Q fragments: wave's 32 q rows = tile qt
  const int qt = qg * 4 + wave;  // 0..127
  bf16x8 qf[8];
  {
    const bf16x8* Qp =
        (const bf16x8*)Qf + ((size_t)(b * (NPOS / 32) + qt) * 8) * 64 + lane;
#pragma unroll
    for (int kf = 0; kf < 8; kf++) qf[kf] = Qp[kf * 64];
  }

  // K tile base for this (b, split): tiles are 8*512 bf16 = 8 KB each
  const __bf16* Ktb =
      Kf + ((size_t)(b * (NPOS / 32) + (kbase >> 5)) * 8) * 512;

  // wave w stages chunks 2w, 2w+1 of each tile (2 DMA insts per wave/tile)
  auto issue = [&](int t, int buf) {
    const __bf16* g = Ktb + (size_t)t * (8 * 512);
#pragma unroll
    for (int cc = 0; cc < 2; cc++) {
      int chunk = wave * 2 + cc;
      async_copy16(g + chunk * 512 + lane * 8,
                   &Klds[buf][chunk * 512 + lane * 8]);
    }
  };
  issue(0, 0);
  issue(1, 1);

  float ls[16];
  f32x2 av[16];
#pragma unroll
  for (int r = 0; r < 16; r++) {
    ls[r] = 0.f;
    av[r] = f32x2{0.f, 0.f};
  }

  int bcur = 0, bnext = 2;  // buffer of tile t; buffer for tile t+2
  for (int t = 0; t < NT; t++) {
    // waits tile t's DMAs (oldest 2 beyond the allowed 2 outstanding) and all
    // LDS ops; leaves tile t+1's DMA in flight across the barrier.
    PIPE_BARRIER(2);
    if (t + 2 < NT) issue(t + 2, bnext);

    const __bf16* kb = &Klds[bcur][0];
    f32x16 c = {0.f, 0.f, 0.f, 0.f, 0.f, 0.f, 0.f, 0.f,
                0.f, 0.f, 0.f, 0.f, 0.f, 0.f, 0.f, 0.f};
#pragma unroll
    for (int kf = 0; kf < 8; kf++) {
      bf16x8 bfrag = *(const bf16x8*)(kb + kf * 512 + lane * 8);
      c = __builtin_amdgcn_mfma_f32_32x32x16_bf16(qf[kf], bfrag, c, 0, 0, 0);
    }
    const f32x2 v01 = {flds[t * 32 + l31], flds[512 + t * 32 + l31]};
#pragma unroll
    for (int r = 0; r < 16; r++) {
      float p = __builtin_amdgcn_exp2f(c[r]);
      ls[r] += p;
      av[r] += f32x2{p, p} * v01;  // v_pk_fma_f32
    }
    bcur = (bcur == 2) ? 0 : bcur + 1;
    bnext = (bnext == 2) ? 0 : bnext + 1;
  }

  // reduce across the 32 key-lanes (butterfly stays within each 32-lane half)
#pragma unroll
  for (int r = 0; r < 16; r++) {
#pragma unroll
    for (int st = 1; st < 32; st <<= 1) {
      ls[r] += __shfl_xor(ls[r], st, 64);
      av[r][0] += __shfl_xor(av[r][0], st, 64);
      av[r][1] += __shfl_xor(av[r][1], st, 64);
    }
  }
  if (l31 == 0) {
#pragma unroll
    for (int r = 0; r < 16; r++) {
      int ql = wave * 32 + (r & 3) + 8 * (r >> 2) + 4 * half;
      red[ql * 3 + 0] = ls[r];
      red[ql * 3 + 1] = av[r][0];
      red[ql * 3 + 2] = av[r][1];
    }
  }
  __syncthreads();
  for (int idx = tid; idx < 128 * 3; idx += 256) {
    int plane = idx / 128, ql = idx % 128;
    part[((size_t)(plane * SPLITS + split) * NB + b) * NPOS + qg * 128 + ql] =
        red[ql * 3 + plane];
  }
}

// ---------------------------------------------------------------------------
// Combine: sum split partials per plane, normalize, write out[b][2][n].
// ---------------------------------------------------------------------------
__global__ __launch_bounds__(256) void combine_kernel(
    const float* __restrict__ part, float* __restrict__ out) {
  int t = blockIdx.x * 256 + threadIdx.x;  // 0 .. NB*NPOS-1
  int b = t >> 12, q = t & (NPOS - 1);
  float l = 0.f, x = 0.f, y = 0.f;
#pragma unroll
  for (int s = 0; s < SPLITS; s++) {
    l += part[((size_t)(0 * SPLITS + s) * NB + b) * NPOS + q];
    x += part[((size_t)(1 * SPLITS + s) * NB + b) * NPOS + q];
    y += part[((size_t)(2 * SPLITS + s) * NB + b) * NPOS + q];
  }
  float inv = 1.0f / l;
  out[(size_t)(b * 2 + 0) * NPOS + q] = x * inv;
  out[(size_t)(b * 2 + 1) * NPOS + q] = y * inv;
}

extern "C" void kernel_launch(void* const* d_in, const int* in_sizes, int n_in,
                              void* d_out, int out_size, void* d_ws,
                              size_t ws_size, hipStream_t stream) {
  const float* feature0 = (const float*)d_in[0];
  const float* flow = (const float*)d_in[1];
  const float* Wq = (const float*)d_in[2];
  const float* bq = (const float*)d_in[3];
  const float* Wk = (const float*)d_in[4];
  const float* bk = (const float*)d_in[5];
  float* out = (float*)d_out;

  char* ws = (char*)d_ws;
  __bf16* Qf = (__bf16*)ws;                                 // 4 MB
  __bf16* Kf = (__bf16*)(ws + (4 << 20));                   // 4 MB
  __bf16* Wqb = (__bf16*)(ws + (8 << 20));                  // 32 KB
  __bf16* Wqkb = (__bf16*)(ws + (8 << 20) + (32 << 10));    // 32 KB
  float* bqk = (float*)(ws + (8 << 20) + (64 << 10));       // 512 B
  float* part = (float*)(ws + (8 << 20) + (128 << 10));     // 1.5 MB

  fuse_w_kernel<<<dim3(CH), 128, 0, stream>>>(Wq, bq, Wk, bk, Wqb, Wqkb, bqk);
  proj_kernel<<<dim3(512), 64, 0, stream>>>(feature0, Wqb, bq, Wqkb, bqk, Qf,
                                            Kf);
  attn_kernel<<<dim3(1024), 256, 0, stream>>>(Qf, Kf, flow, part);
  combine_kernel<<<dim3(NB * NPOS / 256), 256, 0, stream>>>(part, out);
}